// Round 1
// baseline (1699.282 us; speedup 1.0000x reference)
//
#include <hip/hip_runtime.h>

#define B_   2048
#define N_   1024
#define BETA 0.001f
#define VAR_MIN 1e-7f

// fast softplus for the hot kernel (tolerance on final scalar is ~2%)
__device__ __forceinline__ float softplus_fast(float x) {
    return x > 20.f ? x : log1pf(__expf(x));
}
// accurate softplus for the tiny final kernel
__device__ __forceinline__ float softplus_ref(float x) {
    return x > 20.f ? x : log1pf(expf(x));
}

// Fully unrolled per-point MLP: x[32] -> relu(xW1+b1) -> relu(hW2+b2)
// -> mu[8] = gWmu+bmu, iv[8] = 1/max(softplus(gWv+bv), VAR_MIN)
__device__ __forceinline__ void mlp_point(
    const float (&x)[32],
    const float* __restrict__ W1, const float* __restrict__ b1,
    const float* __restrict__ W2, const float* __restrict__ b2,
    const float* __restrict__ Wmu, const float* __restrict__ bmu,
    const float* __restrict__ Wv,  const float* __restrict__ bv,
    float (&mu)[8], float (&iv)[8])
{
    float h[32];
#pragma unroll
    for (int j = 0; j < 32; j++) h[j] = b1[j];
#pragma unroll
    for (int i = 0; i < 32; i++) {
        const float xv = x[i];
#pragma unroll
        for (int j = 0; j < 32; j++) h[j] = fmaf(xv, W1[i * 32 + j], h[j]);
    }
#pragma unroll
    for (int j = 0; j < 32; j++) h[j] = fmaxf(h[j], 0.f);

    float g[32];
#pragma unroll
    for (int j = 0; j < 32; j++) g[j] = b2[j];
#pragma unroll
    for (int i = 0; i < 32; i++) {
        const float hv = h[i];
#pragma unroll
        for (int j = 0; j < 32; j++) g[j] = fmaf(hv, W2[i * 32 + j], g[j]);
    }
#pragma unroll
    for (int j = 0; j < 32; j++) g[j] = fmaxf(g[j], 0.f);

    float vv[8];
#pragma unroll
    for (int z = 0; z < 8; z++) { mu[z] = bmu[z]; vv[z] = bv[z]; }
#pragma unroll
    for (int i = 0; i < 32; i++) {
        const float gv = g[i];
#pragma unroll
        for (int z = 0; z < 8; z++) {
            mu[z] = fmaf(gv, Wmu[i * 8 + z], mu[z]);
            vv[z] = fmaf(gv, Wv[i * 8 + z], vv[z]);
        }
    }
#pragma unroll
    for (int z = 0; z < 8; z++) {
        float var = fmaxf(softplus_fast(vv[z]), VAR_MIN);
        iv[z] = 1.0f / var;
    }
}

// wave-reduce mu[8], iv[8] and accumulate into the block's LDS slots
__device__ __forceinline__ void reduce_and_acc(
    float (&mu)[8], float (&iv)[8], float* sacc, int c)
{
    const int lane = threadIdx.x & 63;
#pragma unroll
    for (int z = 0; z < 8; z++) {
        float m = mu[z];
        float v = iv[z];
#pragma unroll
        for (int off = 32; off; off >>= 1) {
            m += __shfl_down(m, off);
            v += __shfl_down(v, off);
        }
        if (lane == 0) {
            atomicAdd(&sacc[c * 8 + z], m);
            atomicAdd(&sacc[16 + c * 8 + z], v);
        }
    }
}

// Kernel 1: per-point MLP over [B][N], both channels, partial sums into
// acc[B][32] (0..15: sum mu (c,z); 16..31: sum 1/var (c,z))
extern "C" __global__ void __launch_bounds__(256)
hib_mlp(const float* __restrict__ batch,
        const float* __restrict__ W1, const float* __restrict__ b1,
        const float* __restrict__ W2, const float* __restrict__ b2,
        const float* __restrict__ Wmu, const float* __restrict__ bmu,
        const float* __restrict__ Wv,  const float* __restrict__ bv,
        float* __restrict__ acc)
{
    const int b = blockIdx.x >> 2;                    // 4 n-chunks per b
    const int n = ((blockIdx.x & 3) << 8) + threadIdx.x;

    __shared__ float sacc[32];
    if (threadIdx.x < 32) sacc[threadIdx.x] = 0.f;
    __syncthreads();

    // batch layout [B][32][N][2] viewed as float2[B][32][N]
    const float2* __restrict__ bp = (const float2*)batch;
    const size_t base = (size_t)b * 32 * N_ + n;
    float x0[32], x1[32];
#pragma unroll
    for (int i = 0; i < 32; i++) {
        float2 v = bp[base + (size_t)i * N_];
        x0[i] = v.x;
        x1[i] = v.y;
    }

    float mu[8], iv[8];
    mlp_point(x0, W1, b1, W2, b2, Wmu, bmu, Wv, bv, mu, iv);
    reduce_and_acc(mu, iv, sacc, 0);
    mlp_point(x1, W1, b1, W2, b2, Wmu, bmu, Wv, bv, mu, iv);
    reduce_and_acc(mu, iv, sacc, 1);

    __syncthreads();
    if (threadIdx.x < 32)
        atomicAdd(&acc[(size_t)b * 32 + threadIdx.x], sacc[threadIdx.x]);
}

// Kernel 2: per-b pooling -> KL + sampled pairwise loss -> scalar
extern "C" __global__ void __launch_bounds__(256)
hib_final(const float* __restrict__ acc,
          const int* __restrict__ labels,
          const float* __restrict__ eps1, const float* __restrict__ eps2,
          const float* __restrict__ sw, const float* __restrict__ sb,
          float* __restrict__ out)
{
    const int b = blockIdx.x * 256 + threadIdx.x;
    float contrib = 0.f;
    if (b < B_) {
        const float a   = softplus_ref(sw[0]);
        const float sbv = sb[0];

        float muv[2][8], sig[2][8];
        float klsum = 0.f;
#pragma unroll
        for (int c = 0; c < 2; c++) {
#pragma unroll
            for (int z = 0; z < 8; z++) {
                float m   = acc[(size_t)b * 32 + c * 8 + z];
                float ivv = acc[(size_t)b * 32 + 16 + c * 8 + z];
                float var = 1.0f / ivv;
                klsum += -0.5f * logf(var) + 0.5f * (var + m * m) - 0.5f;
                muv[c][z] = m;
                sig[c][z] = sqrtf(var);
            }
        }

        float z1[8][8], z2[8][8];
#pragma unroll
        for (int s = 0; s < 8; s++) {
#pragma unroll
            for (int z = 0; z < 8; z++) {
                z1[s][z] = muv[0][z] + sig[0][z] * eps1[((size_t)b * 8 + s) * 8 + z];
                z2[s][z] = muv[1][z] + sig[1][z] * eps2[((size_t)b * 8 + s) * 8 + z];
            }
        }

        float lsum = 0.f;
#pragma unroll
        for (int i = 0; i < 8; i++) {
#pragma unroll
            for (int j = 0; j < 8; j++) {
                float d2 = 0.f;
#pragma unroll
                for (int z = 0; z < 8; z++) {
                    float d = z1[i][z] - z2[j][z];
                    d2 = fmaf(d, d, d2);
                }
                float dist = sqrtf(d2);
                // -log(sigmoid(-a*dist + sb)) == softplus(a*dist - sb)
                lsum += softplus_ref(a * dist - sbv);
            }
        }

        const float lab = (float)labels[b];
        contrib = klsum * (BETA / (B_ * 8.0f))
                + (lsum * (1.0f / 64.0f)) * lab * (1.0f / B_);
    }
#pragma unroll
    for (int off = 32; off; off >>= 1) contrib += __shfl_down(contrib, off);
    if ((threadIdx.x & 63) == 0) atomicAdd(out, contrib);
}

extern "C" void kernel_launch(void* const* d_in, const int* in_sizes, int n_in,
                              void* d_out, int out_size, void* d_ws, size_t ws_size,
                              hipStream_t stream)
{
    (void)in_sizes; (void)n_in; (void)out_size; (void)ws_size;
    const float* batch  = (const float*)d_in[0];
    const int*   labels = (const int*)  d_in[1];
    const float* eps1   = (const float*)d_in[2];
    const float* eps2   = (const float*)d_in[3];
    const float* W1     = (const float*)d_in[4];
    const float* b1     = (const float*)d_in[5];
    const float* W2     = (const float*)d_in[6];
    const float* b2     = (const float*)d_in[7];
    const float* Wmu    = (const float*)d_in[8];
    const float* bmu    = (const float*)d_in[9];
    const float* Wv     = (const float*)d_in[10];
    const float* bv     = (const float*)d_in[11];
    const float* sw     = (const float*)d_in[12];
    const float* sb     = (const float*)d_in[13];

    float* acc = (float*)d_ws;   // [B][32] partial sums

    hipMemsetAsync(acc, 0, (size_t)B_ * 32 * sizeof(float), stream);
    hipMemsetAsync(d_out, 0, sizeof(float), stream);

    hib_mlp<<<B_ * 4, 256, 0, stream>>>(batch, W1, b1, W2, b2,
                                        Wmu, bmu, Wv, bv, acc);
    hib_final<<<(B_ + 255) / 256, 256, 0, stream>>>(acc, labels, eps1, eps2,
                                                    sw, sb, (float*)d_out);
}

// Round 2
// 635.037 us; speedup vs baseline: 2.6759x; 2.6759x over previous
//
#include <hip/hip_runtime.h>

#define B_   2048
#define N_   1024
#define BETA 0.001f
#define VAR_MIN 1e-7f

__device__ __forceinline__ float softplus_fast(float x) {
    return x > 20.f ? x : log1pf(__expf(x));
}
__device__ __forceinline__ float softplus_ref(float x) {
    return x > 20.f ? x : log1pf(expf(x));
}

__device__ __forceinline__ void fma4(float& d0, float& d1, float& d2, float& d3,
                                     float a, float4 w) {
    d0 = fmaf(a, w.x, d0);
    d1 = fmaf(a, w.y, d1);
    d2 = fmaf(a, w.z, d2);
    d3 = fmaf(a, w.w, d3);
}

// One block per b. 256 threads x 4 chunks = 1024 points, both channels each.
// Weights LDS-resident; wave-uniform float4 broadcast reads.
// sacc[0..7]=sum mu ch0, [8..15]=sum mu ch1, [16..23]=sum 1/var ch0, [24..31]=ch1
__global__ void __launch_bounds__(256)
hib_fused(const float* __restrict__ batch,
          const int* __restrict__ labels,
          const float* __restrict__ eps1, const float* __restrict__ eps2,
          const float* __restrict__ W1, const float* __restrict__ b1,
          const float* __restrict__ W2, const float* __restrict__ b2,
          const float* __restrict__ Wmu, const float* __restrict__ bmu,
          const float* __restrict__ Wv, const float* __restrict__ bv,
          const float* __restrict__ sw, const float* __restrict__ sb,
          float* __restrict__ out)
{
    __shared__ float s[2640 + 32];
    float* sW1  = s;          // 1024
    float* sW2  = s + 1024;   // 1024
    float* sWm  = s + 2048;   // 256
    float* sWvv = s + 2304;   // 256
    float* sB1  = s + 2560;   // 32
    float* sB2  = s + 2592;   // 32
    float* sBm  = s + 2624;   // 8
    float* sBv  = s + 2632;   // 8
    float* sacc = s + 2640;   // 32

    const int tid = threadIdx.x;
    const int b   = blockIdx.x;

    for (int k = tid; k < 1024; k += 256) { sW1[k] = W1[k]; sW2[k] = W2[k]; }
    if (tid < 256) { sWm[tid] = Wmu[tid]; sWvv[tid] = Wv[tid]; }
    if (tid < 32)  { sB1[tid] = b1[tid]; sB2[tid] = b2[tid]; sacc[tid] = 0.f; }
    if (tid < 8)   { sBm[tid] = bmu[tid]; sBv[tid] = bv[tid]; }
    __syncthreads();

    const float2* __restrict__ bp = (const float2*)batch;
    const size_t bbase = (size_t)b * 32 * N_;

#pragma unroll 1
    for (int chunk = 0; chunk < 4; ++chunk) {
        const int n = (chunk << 8) + tid;
        const size_t base = bbase + n;

        // ---- layer 1: h = relu(x W1 + b1), both channels ----
        float h0[32], h1[32];
#pragma unroll
        for (int j = 0; j < 32; j++) { float bb = sB1[j]; h0[j] = bb; h1[j] = bb; }
#pragma unroll 4
        for (int i = 0; i < 32; i++) {
            float2 xi = bp[base + (size_t)i * N_];
            const float* wr = sW1 + i * 32;
#pragma unroll
            for (int q = 0; q < 8; q++) {
                float4 w = *(const float4*)(wr + q * 4);
                fma4(h0[q*4+0], h0[q*4+1], h0[q*4+2], h0[q*4+3], xi.x, w);
                fma4(h1[q*4+0], h1[q*4+1], h1[q*4+2], h1[q*4+3], xi.y, w);
            }
        }
#pragma unroll
        for (int j = 0; j < 32; j++) {
            h0[j] = fmaxf(h0[j], 0.f);
            h1[j] = fmaxf(h1[j], 0.f);
        }

        // ---- layer 2 (16-wide halves) + heads fused ----
        float mu0[8], mu1[8], vv0[8], vv1[8];
#pragma unroll
        for (int z = 0; z < 8; z++) {
            float bm = sBm[z], bvv = sBv[z];
            mu0[z] = bm; mu1[z] = bm; vv0[z] = bvv; vv1[z] = bvv;
        }

#pragma unroll 1
        for (int jh = 0; jh < 2; jh++) {
            float ga[16], gb[16];
#pragma unroll
            for (int j = 0; j < 16; j++) {
                float bb = sB2[jh * 16 + j];
                ga[j] = bb; gb[j] = bb;
            }
#pragma unroll 4
            for (int i = 0; i < 32; i++) {
                float a0 = h0[i], a1 = h1[i];
                const float* wr = sW2 + i * 32 + jh * 16;
#pragma unroll
                for (int q = 0; q < 4; q++) {
                    float4 w = *(const float4*)(wr + q * 4);
                    fma4(ga[q*4+0], ga[q*4+1], ga[q*4+2], ga[q*4+3], a0, w);
                    fma4(gb[q*4+0], gb[q*4+1], gb[q*4+2], gb[q*4+3], a1, w);
                }
            }
            // heads consume this half of g immediately (relu fused)
#pragma unroll 4
            for (int i2 = 0; i2 < 16; i2++) {
                float a0 = fmaxf(ga[i2], 0.f);
                float a1 = fmaxf(gb[i2], 0.f);
                const int i = jh * 16 + i2;
                float4 wm0 = *(const float4*)(sWm  + i * 8);
                float4 wm1 = *(const float4*)(sWm  + i * 8 + 4);
                float4 wv0 = *(const float4*)(sWvv + i * 8);
                float4 wv1 = *(const float4*)(sWvv + i * 8 + 4);
                fma4(mu0[0], mu0[1], mu0[2], mu0[3], a0, wm0);
                fma4(mu0[4], mu0[5], mu0[6], mu0[7], a0, wm1);
                fma4(mu1[0], mu1[1], mu1[2], mu1[3], a1, wm0);
                fma4(mu1[4], mu1[5], mu1[6], mu1[7], a1, wm1);
                fma4(vv0[0], vv0[1], vv0[2], vv0[3], a0, wv0);
                fma4(vv0[4], vv0[5], vv0[6], vv0[7], a0, wv1);
                fma4(vv1[0], vv1[1], vv1[2], vv1[3], a1, wv0);
                fma4(vv1[4], vv1[5], vv1[6], vv1[7], a1, wv1);
            }
        }

        // ---- 1/var per point, wave reduce, accumulate in LDS ----
        float q0[8], q1[8];
#pragma unroll
        for (int z = 0; z < 8; z++) {
            q0[z] = 1.0f / fmaxf(softplus_fast(vv0[z]), VAR_MIN);
            q1[z] = 1.0f / fmaxf(softplus_fast(vv1[z]), VAR_MIN);
        }
#pragma unroll
        for (int z = 0; z < 8; z++) {
            float m0 = mu0[z], m1 = mu1[z], v0 = q0[z], v1 = q1[z];
#pragma unroll
            for (int off = 32; off; off >>= 1) {
                m0 += __shfl_down(m0, off);
                m1 += __shfl_down(m1, off);
                v0 += __shfl_down(v0, off);
                v1 += __shfl_down(v1, off);
            }
            if ((tid & 63) == 0) {
                atomicAdd(&sacc[z],      m0);
                atomicAdd(&sacc[8 + z],  m1);
                atomicAdd(&sacc[16 + z], v0);
                atomicAdd(&sacc[24 + z], v1);
            }
        }
    }
    __syncthreads();

    // ---- per-b tail on wave 0: pooling, KL, S x S sampled loss ----
    if (tid < 64) {
        const float a    = softplus_ref(sw[0]);
        const float sbv_ = sb[0];

        float muA[8], muB[8], sgA[8], sgB[8];
#pragma unroll
        for (int z = 0; z < 8; z++) {
            muA[z] = sacc[z];
            muB[z] = sacc[8 + z];
            sgA[z] = sqrtf(1.0f / sacc[16 + z]);
            sgB[z] = sqrtf(1.0f / sacc[24 + z]);
        }
        const int i = tid >> 3, j = tid & 7;
        float d2 = 0.f;
#pragma unroll
        for (int z = 0; z < 8; z++) {
            float e1 = eps1[((size_t)b * 8 + i) * 8 + z];
            float e2 = eps2[((size_t)b * 8 + j) * 8 + z];
            float zz1 = fmaf(sgA[z], e1, muA[z]);
            float zz2 = fmaf(sgB[z], e2, muB[z]);
            float d = zz1 - zz2;
            d2 = fmaf(d, d, d2);
        }
        const float lab = (float)labels[b];
        // -log(sigmoid(-a*dist + sb)) == softplus(a*dist - sb)
        float contrib = softplus_ref(a * sqrtf(d2) - sbv_) * lab * (1.0f / (64.0f * (float)B_));

        if (tid < 16) {
            const int c = tid >> 3, z = tid & 7;
            float iv  = sacc[16 + c * 8 + z];
            float var = 1.0f / iv;
            float m   = sacc[c * 8 + z];
            contrib += (-0.5f * logf(var) + 0.5f * (var + m * m) - 0.5f)
                       * (BETA / (8.0f * (float)B_));
        }
#pragma unroll
        for (int off = 32; off; off >>= 1) contrib += __shfl_down(contrib, off);
        if (tid == 0) atomicAdd(out, contrib);
    }
}

extern "C" void kernel_launch(void* const* d_in, const int* in_sizes, int n_in,
                              void* d_out, int out_size, void* d_ws, size_t ws_size,
                              hipStream_t stream)
{
    (void)in_sizes; (void)n_in; (void)out_size; (void)d_ws; (void)ws_size;
    const float* batch  = (const float*)d_in[0];
    const int*   labels = (const int*)  d_in[1];
    const float* eps1   = (const float*)d_in[2];
    const float* eps2   = (const float*)d_in[3];
    const float* W1     = (const float*)d_in[4];
    const float* b1     = (const float*)d_in[5];
    const float* W2     = (const float*)d_in[6];
    const float* b2     = (const float*)d_in[7];
    const float* Wmu    = (const float*)d_in[8];
    const float* bmu    = (const float*)d_in[9];
    const float* Wv     = (const float*)d_in[10];
    const float* bv     = (const float*)d_in[11];
    const float* sw     = (const float*)d_in[12];
    const float* sb     = (const float*)d_in[13];

    hipMemsetAsync(d_out, 0, sizeof(float), stream);
    hib_fused<<<B_, 256, 0, stream>>>(batch, labels, eps1, eps2,
                                      W1, b1, W2, b2, Wmu, bmu, Wv, bv,
                                      sw, sb, (float*)d_out);
}

// Round 3
// 392.994 us; speedup vs baseline: 4.3239x; 1.6159x over previous
//
#include <hip/hip_runtime.h>

#define B_   2048
#define N_   1024
#define BETA 0.001f
#define VAR_MIN 1e-7f

__device__ __forceinline__ float softplus_fast(float x) {
    return x > 20.f ? x : log1pf(__expf(x));
}
__device__ __forceinline__ float softplus_ref(float x) {
    return x > 20.f ? x : log1pf(expf(x));
}

__device__ __forceinline__ void fma4(float& d0, float& d1, float& d2, float& d3,
                                     float a, float4 w) {
    d0 = fmaf(a, w.x, d0);
    d1 = fmaf(a, w.y, d1);
    d2 = fmaf(a, w.z, d2);
    d3 = fmaf(a, w.w, d3);
}

// One block per b. 256 threads x 4 chunks = 1024 points, both channels each.
// Weights read as wave-uniform global loads -> s_load through K$ (SMEM pipe);
// v_fma takes the weight as its SGPR operand. DS pipe carries only sacc[32].
__global__ void __launch_bounds__(256)
hib_fused(const float* __restrict__ batch,
          const int* __restrict__ labels,
          const float* __restrict__ eps1, const float* __restrict__ eps2,
          const float* __restrict__ W1, const float* __restrict__ b1,
          const float* __restrict__ W2, const float* __restrict__ b2,
          const float* __restrict__ Wmu, const float* __restrict__ bmu,
          const float* __restrict__ Wv, const float* __restrict__ bv,
          const float* __restrict__ sw, const float* __restrict__ sb,
          float* __restrict__ out)
{
    __shared__ float sacc[32];
    const int tid = threadIdx.x;
    const int b   = blockIdx.x;

    if (tid < 32) sacc[tid] = 0.f;
    __syncthreads();

    const float2* __restrict__ bp = (const float2*)batch;
    const size_t bbase = (size_t)b * 32 * N_;

    const float4* __restrict__ W1v = (const float4*)W1;   // [32][8] float4
    const float4* __restrict__ W2v = (const float4*)W2;   // [32][8] float4
    const float4* __restrict__ Wmv = (const float4*)Wmu;  // [32][2] float4
    const float4* __restrict__ Wvv = (const float4*)Wv;   // [32][2] float4

#pragma unroll 1
    for (int chunk = 0; chunk < 4; ++chunk) {
        const int n = (chunk << 8) + tid;
        const size_t base = bbase + n;

        // ---- layer 1: h = relu(x W1 + b1), both channels ----
        float h0[32], h1[32];
#pragma unroll
        for (int j = 0; j < 32; j++) { float bb = b1[j]; h0[j] = bb; h1[j] = bb; }
#pragma unroll 4
        for (int i = 0; i < 32; i++) {
            float2 xi = bp[base + (size_t)i * N_];
#pragma unroll
            for (int q = 0; q < 8; q++) {
                float4 w = W1v[i * 8 + q];
                fma4(h0[q*4+0], h0[q*4+1], h0[q*4+2], h0[q*4+3], xi.x, w);
                fma4(h1[q*4+0], h1[q*4+1], h1[q*4+2], h1[q*4+3], xi.y, w);
            }
        }
#pragma unroll
        for (int j = 0; j < 32; j++) {
            h0[j] = fmaxf(h0[j], 0.f);
            h1[j] = fmaxf(h1[j], 0.f);
        }

        // ---- layer 2 (16-wide halves) + heads fused ----
        float mu0[8], mu1[8], vv0[8], vv1[8];
#pragma unroll
        for (int z = 0; z < 8; z++) {
            float bm = bmu[z], bvv = bv[z];
            mu0[z] = bm; mu1[z] = bm; vv0[z] = bvv; vv1[z] = bvv;
        }

#pragma unroll 1
        for (int jh = 0; jh < 2; jh++) {
            float ga[16], gb[16];
#pragma unroll
            for (int j = 0; j < 16; j++) {
                float bb = b2[jh * 16 + j];
                ga[j] = bb; gb[j] = bb;
            }
#pragma unroll 4
            for (int i = 0; i < 32; i++) {
                float a0 = h0[i], a1 = h1[i];
#pragma unroll
                for (int q = 0; q < 4; q++) {
                    float4 w = W2v[i * 8 + jh * 4 + q];
                    fma4(ga[q*4+0], ga[q*4+1], ga[q*4+2], ga[q*4+3], a0, w);
                    fma4(gb[q*4+0], gb[q*4+1], gb[q*4+2], gb[q*4+3], a1, w);
                }
            }
            // heads consume this half of g immediately (relu fused)
#pragma unroll 4
            for (int i2 = 0; i2 < 16; i2++) {
                float a0 = fmaxf(ga[i2], 0.f);
                float a1 = fmaxf(gb[i2], 0.f);
                const int i = jh * 16 + i2;
                float4 wm0 = Wmv[i * 2];
                float4 wm1 = Wmv[i * 2 + 1];
                float4 wv0 = Wvv[i * 2];
                float4 wv1 = Wvv[i * 2 + 1];
                fma4(mu0[0], mu0[1], mu0[2], mu0[3], a0, wm0);
                fma4(mu0[4], mu0[5], mu0[6], mu0[7], a0, wm1);
                fma4(mu1[0], mu1[1], mu1[2], mu1[3], a1, wm0);
                fma4(mu1[4], mu1[5], mu1[6], mu1[7], a1, wm1);
                fma4(vv0[0], vv0[1], vv0[2], vv0[3], a0, wv0);
                fma4(vv0[4], vv0[5], vv0[6], vv0[7], a0, wv1);
                fma4(vv1[0], vv1[1], vv1[2], vv1[3], a1, wv0);
                fma4(vv1[4], vv1[5], vv1[6], vv1[7], a1, wv1);
            }
        }

        // ---- 1/var per point, wave reduce, accumulate in LDS ----
        float q0[8], q1[8];
#pragma unroll
        for (int z = 0; z < 8; z++) {
            q0[z] = 1.0f / fmaxf(softplus_fast(vv0[z]), VAR_MIN);
            q1[z] = 1.0f / fmaxf(softplus_fast(vv1[z]), VAR_MIN);
        }
#pragma unroll
        for (int z = 0; z < 8; z++) {
            float m0 = mu0[z], m1 = mu1[z], v0 = q0[z], v1 = q1[z];
#pragma unroll
            for (int off = 32; off; off >>= 1) {
                m0 += __shfl_down(m0, off);
                m1 += __shfl_down(m1, off);
                v0 += __shfl_down(v0, off);
                v1 += __shfl_down(v1, off);
            }
            if ((tid & 63) == 0) {
                atomicAdd(&sacc[z],      m0);
                atomicAdd(&sacc[8 + z],  m1);
                atomicAdd(&sacc[16 + z], v0);
                atomicAdd(&sacc[24 + z], v1);
            }
        }
    }
    __syncthreads();

    // ---- per-b tail on wave 0: pooling, KL, S x S sampled loss ----
    if (tid < 64) {
        const float a    = softplus_ref(sw[0]);
        const float sbv_ = sb[0];

        float muA[8], muB[8], sgA[8], sgB[8];
#pragma unroll
        for (int z = 0; z < 8; z++) {
            muA[z] = sacc[z];
            muB[z] = sacc[8 + z];
            sgA[z] = sqrtf(1.0f / sacc[16 + z]);
            sgB[z] = sqrtf(1.0f / sacc[24 + z]);
        }
        const int i = tid >> 3, j = tid & 7;
        float d2 = 0.f;
#pragma unroll
        for (int z = 0; z < 8; z++) {
            float e1 = eps1[((size_t)b * 8 + i) * 8 + z];
            float e2 = eps2[((size_t)b * 8 + j) * 8 + z];
            float zz1 = fmaf(sgA[z], e1, muA[z]);
            float zz2 = fmaf(sgB[z], e2, muB[z]);
            float d = zz1 - zz2;
            d2 = fmaf(d, d, d2);
        }
        const float lab = (float)labels[b];
        // -log(sigmoid(-a*dist + sb)) == softplus(a*dist - sb)
        float contrib = softplus_ref(a * sqrtf(d2) - sbv_) * lab * (1.0f / (64.0f * (float)B_));

        if (tid < 16) {
            const int c = tid >> 3, z = tid & 7;
            float iv  = sacc[16 + c * 8 + z];
            float var = 1.0f / iv;
            float m   = sacc[c * 8 + z];
            contrib += (-0.5f * logf(var) + 0.5f * (var + m * m) - 0.5f)
                       * (BETA / (8.0f * (float)B_));
        }
#pragma unroll
        for (int off = 32; off; off >>= 1) contrib += __shfl_down(contrib, off);
        if (tid == 0) atomicAdd(out, contrib);
    }
}

extern "C" void kernel_launch(void* const* d_in, const int* in_sizes, int n_in,
                              void* d_out, int out_size, void* d_ws, size_t ws_size,
                              hipStream_t stream)
{
    (void)in_sizes; (void)n_in; (void)out_size; (void)d_ws; (void)ws_size;
    const float* batch  = (const float*)d_in[0];
    const int*   labels = (const int*)  d_in[1];
    const float* eps1   = (const float*)d_in[2];
    const float* eps2   = (const float*)d_in[3];
    const float* W1     = (const float*)d_in[4];
    const float* b1     = (const float*)d_in[5];
    const float* W2     = (const float*)d_in[6];
    const float* b2     = (const float*)d_in[7];
    const float* Wmu    = (const float*)d_in[8];
    const float* bmu    = (const float*)d_in[9];
    const float* Wv     = (const float*)d_in[10];
    const float* bv     = (const float*)d_in[11];
    const float* sw     = (const float*)d_in[12];
    const float* sb     = (const float*)d_in[13];

    hipMemsetAsync(d_out, 0, sizeof(float), stream);
    hib_fused<<<B_, 256, 0, stream>>>(batch, labels, eps1, eps2,
                                      W1, b1, W2, b2, Wmu, bmu, Wv, bv,
                                      sw, sb, (float*)d_out);
}

// Round 4
// 273.669 us; speedup vs baseline: 6.2093x; 1.4360x over previous
//
#include <hip/hip_runtime.h>
#include <hip/hip_bf16.h>

#define B_   2048
#define N_   1024
#define BETA 0.001f
#define VAR_MIN 1e-7f
#define STR  36   // LDS row stride in bf16 units (conflict-free + 8B aligned)

typedef __attribute__((ext_vector_type(8))) short  bf16x8;
typedef __attribute__((ext_vector_type(4))) float  f32x4;
typedef __attribute__((ext_vector_type(4))) unsigned int u32x4;

__device__ __forceinline__ unsigned short f2bf_u(float x) {
    __hip_bfloat16 h = __float2bfloat16(x);
    return __builtin_bit_cast(unsigned short, h);
}

__device__ __forceinline__ float softplus_fast(float x) {
    return x > 20.f ? x : log1pf(__expf(x));
}
__device__ __forceinline__ float softplus_ref(float x) {
    return x > 20.f ? x : log1pf(expf(x));
}

// ---- weight prep: pack B-frags (lane l: col=l&15, k=(l>>4)*8+j) ----
// frag 0: W1 cols 0-15 | 1: W1 cols 16-31 | 2: W2 cols 0-15 | 3: W2 cols 16-31
// frag 4: [Wmu | Wv] cols 0-15
extern "C" __global__ void hib_prep(const float* __restrict__ W1,
                                    const float* __restrict__ W2,
                                    const float* __restrict__ Wmu,
                                    const float* __restrict__ Wv,
                                    unsigned short* __restrict__ wf)
{
    const int l = threadIdx.x;         // 0..63
    const int col = l & 15, kb = l >> 4;
#pragma unroll
    for (int j = 0; j < 8; j++) {
        const int k = kb * 8 + j;
        wf[(0 * 64 + l) * 8 + j] = f2bf_u(W1[k * 32 + col]);
        wf[(1 * 64 + l) * 8 + j] = f2bf_u(W1[k * 32 + 16 + col]);
        wf[(2 * 64 + l) * 8 + j] = f2bf_u(W2[k * 32 + col]);
        wf[(3 * 64 + l) * 8 + j] = f2bf_u(W2[k * 32 + 16 + col]);
        wf[(4 * 64 + l) * 8 + j] = f2bf_u(col < 8 ? Wmu[k * 8 + col]
                                                  : Wv[k * 8 + (col - 8)]);
    }
}

// write one 16x16 C-tile (relu + bf16) into [point][feature] LDS tile
__device__ __forceinline__ void wtile(unsigned short* __restrict__ buf,
                                      f32x4 v, int ct, int col, int kb)
{
    const int c  = ct * 16 + col;
    const int r0 = kb * 4;
    buf[(r0 + 0) * STR + c] = f2bf_u(fmaxf(v.x, 0.f));
    buf[(r0 + 1) * STR + c] = f2bf_u(fmaxf(v.y, 0.f));
    buf[(r0 + 2) * STR + c] = f2bf_u(fmaxf(v.z, 0.f));
    buf[(r0 + 3) * STR + c] = f2bf_u(fmaxf(v.w, 0.f));
}

// read A-frag: row = col(l&15) point, k = kb*8 + j
__device__ __forceinline__ bf16x8 rfrag(const unsigned short* __restrict__ buf,
                                        int col, int kb)
{
    const unsigned short* p = buf + col * STR + kb * 8;
    uint2 lo = *(const uint2*)p;
    uint2 hi = *(const uint2*)(p + 4);
    u32x4 t; t.x = lo.x; t.y = lo.y; t.z = hi.x; t.w = hi.y;
    return __builtin_bit_cast(bf16x8, t);
}

__global__ void __launch_bounds__(256)
hib_mfma(const float* __restrict__ batch,
         const int* __restrict__ labels,
         const float* __restrict__ eps1, const float* __restrict__ eps2,
         const unsigned short* __restrict__ wf,
         const float* __restrict__ b1, const float* __restrict__ b2,
         const float* __restrict__ bmu, const float* __restrict__ bv,
         const float* __restrict__ sw, const float* __restrict__ sb,
         float* __restrict__ out)
{
    __shared__ unsigned short tl[4][2][2][16 * STR]; // [wave][ch][H/G]
    __shared__ float sacc[32];

    const int tid = threadIdx.x;
    const int b   = blockIdx.x;
    const int wid = tid >> 6, l = tid & 63;
    const int col = l & 15, kb = l >> 4;

    if (tid < 32) sacc[tid] = 0.f;
    __syncthreads();

    // weight B-frags, held in registers for the whole kernel
    const bf16x8* wfv = (const bf16x8*)wf;
    const bf16x8 w1a = wfv[0 * 64 + l], w1b = wfv[1 * 64 + l];
    const bf16x8 w2a = wfv[2 * 64 + l], w2b = wfv[3 * 64 + l];
    const bf16x8 whd = wfv[4 * 64 + l];

    const float bb1a = b1[col],  bb1b = b1[16 + col];
    const float bb2a = b2[col],  bb2b = b2[16 + col];
    const float bbh  = (col < 8) ? bmu[col] : bv[col - 8];

    unsigned short* H0 = tl[wid][0][0];
    unsigned short* G0 = tl[wid][0][1];
    unsigned short* H1 = tl[wid][1][0];
    unsigned short* G1 = tl[wid][1][1];

    float acc0 = 0.f, acc1 = 0.f;

    // lane's global pointer: batch[b][k=kb*8+j][p][.] as float2
    const float2* lp = (const float2*)batch
                     + (size_t)b * 32 * N_
                     + (size_t)(kb * 8) * N_
                     + wid * 256 + col;

#pragma unroll 1
    for (int t = 0; t < 16; t++) {
        float2 xs[8];
#pragma unroll
        for (int j = 0; j < 8; j++) xs[j] = lp[(size_t)j * N_];
        lp += 16;

        bf16x8 a0, a1;
#pragma unroll
        for (int j = 0; j < 8; j++) {
            a0[j] = (short)f2bf_u(xs[j].x);
            a1[j] = (short)f2bf_u(xs[j].y);
        }

        // ---- layer 1 ----
        f32x4 h00 = {bb1a, bb1a, bb1a, bb1a};
        f32x4 h01 = {bb1b, bb1b, bb1b, bb1b};
        f32x4 h10 = h00, h11 = h01;
        h00 = __builtin_amdgcn_mfma_f32_16x16x32_bf16(a0, w1a, h00, 0, 0, 0);
        h01 = __builtin_amdgcn_mfma_f32_16x16x32_bf16(a0, w1b, h01, 0, 0, 0);
        h10 = __builtin_amdgcn_mfma_f32_16x16x32_bf16(a1, w1a, h10, 0, 0, 0);
        h11 = __builtin_amdgcn_mfma_f32_16x16x32_bf16(a1, w1b, h11, 0, 0, 0);

        wtile(H0, h00, 0, col, kb); wtile(H0, h01, 1, col, kb);
        wtile(H1, h10, 0, col, kb); wtile(H1, h11, 1, col, kb);

        const bf16x8 ha0 = rfrag(H0, col, kb);
        const bf16x8 ha1 = rfrag(H1, col, kb);

        // ---- layer 2 ----
        f32x4 g00 = {bb2a, bb2a, bb2a, bb2a};
        f32x4 g01 = {bb2b, bb2b, bb2b, bb2b};
        f32x4 g10 = g00, g11 = g01;
        g00 = __builtin_amdgcn_mfma_f32_16x16x32_bf16(ha0, w2a, g00, 0, 0, 0);
        g01 = __builtin_amdgcn_mfma_f32_16x16x32_bf16(ha0, w2b, g01, 0, 0, 0);
        g10 = __builtin_amdgcn_mfma_f32_16x16x32_bf16(ha1, w2a, g10, 0, 0, 0);
        g11 = __builtin_amdgcn_mfma_f32_16x16x32_bf16(ha1, w2b, g11, 0, 0, 0);

        wtile(G0, g00, 0, col, kb); wtile(G0, g01, 1, col, kb);
        wtile(G1, g10, 0, col, kb); wtile(G1, g11, 1, col, kb);

        const bf16x8 pa0 = rfrag(G0, col, kb);
        const bf16x8 pa1 = rfrag(G1, col, kb);

        // ---- heads: cols 0-7 mu, 8-15 v ----
        f32x4 e0 = {bbh, bbh, bbh, bbh};
        f32x4 e1 = e0;
        e0 = __builtin_amdgcn_mfma_f32_16x16x32_bf16(pa0, whd, e0, 0, 0, 0);
        e1 = __builtin_amdgcn_mfma_f32_16x16x32_bf16(pa1, whd, e1, 0, 0, 0);

        if (col < 8) {
            acc0 += (e0.x + e0.y) + (e0.z + e0.w);
            acc1 += (e1.x + e1.y) + (e1.z + e1.w);
        } else {
            acc0 += 1.f / fmaxf(softplus_fast(e0.x), VAR_MIN)
                  + 1.f / fmaxf(softplus_fast(e0.y), VAR_MIN)
                  + 1.f / fmaxf(softplus_fast(e0.z), VAR_MIN)
                  + 1.f / fmaxf(softplus_fast(e0.w), VAR_MIN);
            acc1 += 1.f / fmaxf(softplus_fast(e1.x), VAR_MIN)
                  + 1.f / fmaxf(softplus_fast(e1.y), VAR_MIN)
                  + 1.f / fmaxf(softplus_fast(e1.z), VAR_MIN)
                  + 1.f / fmaxf(softplus_fast(e1.w), VAR_MIN);
        }
    }

    // reduce across the 4 row-groups (lanes with same l&15)
    acc0 += __shfl_down(acc0, 32); acc0 += __shfl_down(acc0, 16);
    acc1 += __shfl_down(acc1, 32); acc1 += __shfl_down(acc1, 16);
    if (l < 16) {
        const int i0 = (col < 8) ? col        : (16 + col - 8); // ch0
        const int i1 = (col < 8) ? (8 + col)  : (24 + col - 8); // ch1
        atomicAdd(&sacc[i0], acc0);
        atomicAdd(&sacc[i1], acc1);
    }
    __syncthreads();

    // ---- per-b tail on wave 0: pooling, KL, S x S sampled loss ----
    if (tid < 64) {
        const float a    = softplus_ref(sw[0]);
        const float sbv_ = sb[0];

        float muA[8], muB[8], sgA[8], sgB[8];
#pragma unroll
        for (int z = 0; z < 8; z++) {
            muA[z] = sacc[z];
            muB[z] = sacc[8 + z];
            sgA[z] = sqrtf(1.0f / sacc[16 + z]);
            sgB[z] = sqrtf(1.0f / sacc[24 + z]);
        }
        const int i = tid >> 3, j = tid & 7;
        float d2 = 0.f;
#pragma unroll
        for (int z = 0; z < 8; z++) {
            float e1 = eps1[((size_t)b * 8 + i) * 8 + z];
            float e2 = eps2[((size_t)b * 8 + j) * 8 + z];
            float zz1 = fmaf(sgA[z], e1, muA[z]);
            float zz2 = fmaf(sgB[z], e2, muB[z]);
            float d = zz1 - zz2;
            d2 = fmaf(d, d, d2);
        }
        const float lab = (float)labels[b];
        float contrib = softplus_ref(a * sqrtf(d2) - sbv_) * lab
                      * (1.0f / (64.0f * (float)B_));

        if (tid < 16) {
            const int c = tid >> 3, z = tid & 7;
            float iv  = sacc[16 + c * 8 + z];
            float var = 1.0f / iv;
            float m   = sacc[c * 8 + z];
            contrib += (-0.5f * logf(var) + 0.5f * (var + m * m) - 0.5f)
                       * (BETA / (8.0f * (float)B_));
        }
#pragma unroll
        for (int off = 32; off; off >>= 1) contrib += __shfl_down(contrib, off);
        if (tid == 0) atomicAdd(out, contrib);
    }
}

extern "C" void kernel_launch(void* const* d_in, const int* in_sizes, int n_in,
                              void* d_out, int out_size, void* d_ws, size_t ws_size,
                              hipStream_t stream)
{
    (void)in_sizes; (void)n_in; (void)out_size; (void)ws_size;
    const float* batch  = (const float*)d_in[0];
    const int*   labels = (const int*)  d_in[1];
    const float* eps1   = (const float*)d_in[2];
    const float* eps2   = (const float*)d_in[3];
    const float* W1     = (const float*)d_in[4];
    const float* b1     = (const float*)d_in[5];
    const float* W2     = (const float*)d_in[6];
    const float* b2     = (const float*)d_in[7];
    const float* Wmu    = (const float*)d_in[8];
    const float* bmu    = (const float*)d_in[9];
    const float* Wv     = (const float*)d_in[10];
    const float* bv     = (const float*)d_in[11];
    const float* sw     = (const float*)d_in[12];
    const float* sb     = (const float*)d_in[13];

    unsigned short* wf = (unsigned short*)d_ws;   // 5 frags x 64 lanes x 8 bf16

    hipMemsetAsync(d_out, 0, sizeof(float), stream);
    hib_prep<<<1, 64, 0, stream>>>(W1, W2, Wmu, Wv, wf);
    hib_mfma<<<B_, 256, 0, stream>>>(batch, labels, eps1, eps2, wf,
                                     b1, b2, bmu, bv, sw, sb, (float*)d_out);
}

// Round 5
// 268.448 us; speedup vs baseline: 6.3300x; 1.0194x over previous
//
#include <hip/hip_runtime.h>
#include <hip/hip_bf16.h>

#define B_   2048
#define N_   1024
#define BETA 0.001f
#define VAR_MIN 1e-7f

typedef __attribute__((ext_vector_type(8))) short  bf16x8;
typedef __attribute__((ext_vector_type(4))) float  f32x4;

__device__ __forceinline__ unsigned short f2bf_u(float x) {
    __hip_bfloat16 h = __float2bfloat16(x);
    return __builtin_bit_cast(unsigned short, h);
}
__device__ __forceinline__ float softplus_fast(float x) {
    return x > 20.f ? x : log1pf(__expf(x));
}
__device__ __forceinline__ float softplus_ref(float x) {
    return x > 20.f ? x : log1pf(expf(x));
}

// pi(k): physical feature sitting at contraction position k for layer-2 and
// head A-operands. Chosen so the previous layer's C-layout registers feed the
// next MFMA's B positions with ZERO cross-lane movement:
// C lane-group kb holds features {4kb..4kb+3} (tile a) and {16+4kb..16+4kb+3}
// (tile b); B lane-group kb supplies positions kb*8..kb*8+7.
__device__ __forceinline__ int kperm(int k) {
    return 4 * (k >> 3) + (k & 3) + 16 * ((k >> 2) & 1);
}

// A-frag weight prep (one 64-thread block, runs once per launch).
// lane l: row r = l&15 (output feature), positions (l>>4)*8+j.
// frag0/1: W1^T col-tiles (identity k = input features)
// frag2/3: W2^T col-tiles (k permuted by pi)
// frag4  : [Wmu | Wv]^T rows 0-7 = mu, 8-15 = v   (k permuted by pi)
extern "C" __global__ void hib_prep(const float* __restrict__ W1,
                                    const float* __restrict__ W2,
                                    const float* __restrict__ Wmu,
                                    const float* __restrict__ Wv,
                                    unsigned short* __restrict__ wf)
{
    const int l = threadIdx.x;         // 0..63
    const int r = l & 15, kb = l >> 4;
#pragma unroll
    for (int j = 0; j < 8; j++) {
        const int k1 = kb * 8 + j;
        const int kp = kperm(k1);
        wf[(0 * 64 + l) * 8 + j] = f2bf_u(W1[k1 * 32 + r]);
        wf[(1 * 64 + l) * 8 + j] = f2bf_u(W1[k1 * 32 + 16 + r]);
        wf[(2 * 64 + l) * 8 + j] = f2bf_u(W2[kp * 32 + r]);
        wf[(3 * 64 + l) * 8 + j] = f2bf_u(W2[kp * 32 + 16 + r]);
        wf[(4 * 64 + l) * 8 + j] = f2bf_u(r < 8 ? Wmu[kp * 8 + r]
                                                : Wv[kp * 8 + (r - 8)]);
    }
}

// relu + cvt two C-frags into the next layer's B-frag (pure per-lane)
__device__ __forceinline__ bf16x8 pack_relu(f32x4 a, f32x4 b) {
    bf16x8 o;
    o[0] = (short)f2bf_u(fmaxf(a.x, 0.f));
    o[1] = (short)f2bf_u(fmaxf(a.y, 0.f));
    o[2] = (short)f2bf_u(fmaxf(a.z, 0.f));
    o[3] = (short)f2bf_u(fmaxf(a.w, 0.f));
    o[4] = (short)f2bf_u(fmaxf(b.x, 0.f));
    o[5] = (short)f2bf_u(fmaxf(b.y, 0.f));
    o[6] = (short)f2bf_u(fmaxf(b.z, 0.f));
    o[7] = (short)f2bf_u(fmaxf(b.w, 0.f));
    return o;
}

// full per-point-tile chain for one channel: X-frag -> heads, all in regs
__device__ __forceinline__ void point_chain(
    const float (&x)[8],
    bf16x8 A1a, bf16x8 A1b, bf16x8 A2a, bf16x8 A2b, bf16x8 Ahd,
    f32x4 c1a, f32x4 c1b, f32x4 c2a, f32x4 c2b, f32x4 chd,
    bool is_v, f32x4& acc)
{
    bf16x8 bx;
#pragma unroll
    for (int j = 0; j < 8; j++) bx[j] = (short)f2bf_u(x[j]);
    f32x4 d1a = __builtin_amdgcn_mfma_f32_16x16x32_bf16(A1a, bx, c1a, 0, 0, 0);
    f32x4 d1b = __builtin_amdgcn_mfma_f32_16x16x32_bf16(A1b, bx, c1b, 0, 0, 0);
    bf16x8 b2 = pack_relu(d1a, d1b);
    f32x4 d2a = __builtin_amdgcn_mfma_f32_16x16x32_bf16(A2a, b2, c2a, 0, 0, 0);
    f32x4 d2b = __builtin_amdgcn_mfma_f32_16x16x32_bf16(A2b, b2, c2b, 0, 0, 0);
    bf16x8 b3 = pack_relu(d2a, d2b);
    f32x4 e   = __builtin_amdgcn_mfma_f32_16x16x32_bf16(Ahd, b3, chd, 0, 0, 0);
    if (!is_v) {
        acc.x += e.x; acc.y += e.y; acc.z += e.z; acc.w += e.w;
    } else {
        acc.x += 1.f / fmaxf(softplus_fast(e.x), VAR_MIN);
        acc.y += 1.f / fmaxf(softplus_fast(e.y), VAR_MIN);
        acc.z += 1.f / fmaxf(softplus_fast(e.z), VAR_MIN);
        acc.w += 1.f / fmaxf(softplus_fast(e.w), VAR_MIN);
    }
}

__device__ __forceinline__ void red16(f32x4& v) {
#pragma unroll
    for (int off = 8; off; off >>= 1) {
        v.x += __shfl_down(v.x, off);
        v.y += __shfl_down(v.y, off);
        v.z += __shfl_down(v.z, off);
        v.w += __shfl_down(v.w, off);
    }
}

__global__ void __launch_bounds__(256)
hib_mfma(const float* __restrict__ batch,
         const int* __restrict__ labels,
         const float* __restrict__ eps1, const float* __restrict__ eps2,
         const unsigned short* __restrict__ wf,
         const float* __restrict__ b1, const float* __restrict__ b2,
         const float* __restrict__ bmu, const float* __restrict__ bv,
         const float* __restrict__ sw, const float* __restrict__ sb,
         float* __restrict__ out)
{
    __shared__ float sacc[32];
    const int tid = threadIdx.x;
    const int b   = blockIdx.x;
    const int wid = tid >> 6, l = tid & 63;
    const int c   = l & 15, kb = l >> 4;

    if (tid < 32) sacc[tid] = 0.f;
    __syncthreads();

    // weight A-frags, register-resident for the whole kernel
    const bf16x8* wfv = (const bf16x8*)wf;
    const bf16x8 A1a = wfv[0 * 64 + l], A1b = wfv[1 * 64 + l];
    const bf16x8 A2a = wfv[2 * 64 + l], A2b = wfv[3 * 64 + l];
    const bf16x8 Ahd = wfv[4 * 64 + l];

    // bias accumulator inits: C rows = 4*kb + i
    const int r4 = 4 * kb;
    const bool is_v = (kb >= 2);
    const int  z4   = 4 * (kb & 1);
    f32x4 c1a, c1b, c2a, c2b, chd;
    c1a.x = b1[r4];      c1a.y = b1[r4 + 1];      c1a.z = b1[r4 + 2];      c1a.w = b1[r4 + 3];
    c1b.x = b1[16 + r4]; c1b.y = b1[16 + r4 + 1]; c1b.z = b1[16 + r4 + 2]; c1b.w = b1[16 + r4 + 3];
    c2a.x = b2[r4];      c2a.y = b2[r4 + 1];      c2a.z = b2[r4 + 2];      c2a.w = b2[r4 + 3];
    c2b.x = b2[16 + r4]; c2b.y = b2[16 + r4 + 1]; c2b.z = b2[16 + r4 + 2]; c2b.w = b2[16 + r4 + 3];
    if (is_v) { chd.x = bv[z4];  chd.y = bv[z4 + 1];  chd.z = bv[z4 + 2];  chd.w = bv[z4 + 3]; }
    else      { chd.x = bmu[z4]; chd.y = bmu[z4 + 1]; chd.z = bmu[z4 + 2]; chd.w = bmu[z4 + 3]; }

    f32x4 acc0 = {0.f, 0.f, 0.f, 0.f};
    f32x4 acc1 = {0.f, 0.f, 0.f, 0.f};

    // lane's stream: batch[b][kb*8+j][wid*256 + t*16 + c] as float2 (both ch)
    const float2* lp = (const float2*)batch
                     + (size_t)b * 32 * N_
                     + (size_t)(kb * 8) * N_
                     + wid * 256 + c;

    float2 xs[8];
#pragma unroll
    for (int j = 0; j < 8; j++) xs[j] = lp[(size_t)j * N_];

#pragma unroll 1
    for (int t = 0; t < 16; t++) {
        // prefetch next tile (clamped pointer on the last iteration)
        const float2* lpn = lp + ((t < 15) ? 16 : 0);
        float2 xn[8];
#pragma unroll
        for (int j = 0; j < 8; j++) xn[j] = lpn[(size_t)j * N_];

        float x0[8], x1[8];
#pragma unroll
        for (int j = 0; j < 8; j++) { x0[j] = xs[j].x; x1[j] = xs[j].y; }

        point_chain(x0, A1a, A1b, A2a, A2b, Ahd, c1a, c1b, c2a, c2b, chd,
                    is_v, acc0);
        point_chain(x1, A1a, A1b, A2a, A2b, Ahd, c1a, c1b, c2a, c2b, chd,
                    is_v, acc1);

#pragma unroll
        for (int j = 0; j < 8; j++) xs[j] = xn[j];
        lp += 16;
    }

    // reduce over the 16 point-columns within each lane group
    red16(acc0);
    red16(acc1);

    if (c == 0) {
        const int base = (is_v ? 16 : 0) + z4;   // +0: ch0, +8: ch1
        atomicAdd(&sacc[base + 0],     acc0.x);
        atomicAdd(&sacc[base + 1],     acc0.y);
        atomicAdd(&sacc[base + 2],     acc0.z);
        atomicAdd(&sacc[base + 3],     acc0.w);
        atomicAdd(&sacc[base + 8 + 0], acc1.x);
        atomicAdd(&sacc[base + 8 + 1], acc1.y);
        atomicAdd(&sacc[base + 8 + 2], acc1.z);
        atomicAdd(&sacc[base + 8 + 3], acc1.w);
    }
    __syncthreads();

    // ---- per-b tail on wave 0: pooling, KL, S x S sampled loss ----
    if (tid < 64) {
        const float a    = softplus_ref(sw[0]);
        const float sbv_ = sb[0];

        float muA[8], muB[8], sgA[8], sgB[8];
#pragma unroll
        for (int z = 0; z < 8; z++) {
            muA[z] = sacc[z];
            muB[z] = sacc[8 + z];
            sgA[z] = sqrtf(1.0f / sacc[16 + z]);
            sgB[z] = sqrtf(1.0f / sacc[24 + z]);
        }
        const int i = tid >> 3, j = tid & 7;
        float d2 = 0.f;
#pragma unroll
        for (int z = 0; z < 8; z++) {
            float e1 = eps1[((size_t)b * 8 + i) * 8 + z];
            float e2 = eps2[((size_t)b * 8 + j) * 8 + z];
            float zz1 = fmaf(sgA[z], e1, muA[z]);
            float zz2 = fmaf(sgB[z], e2, muB[z]);
            float d = zz1 - zz2;
            d2 = fmaf(d, d, d2);
        }
        const float lab = (float)labels[b];
        float contrib = softplus_ref(a * sqrtf(d2) - sbv_) * lab
                      * (1.0f / (64.0f * (float)B_));

        if (tid < 16) {
            const int cc = tid >> 3, z = tid & 7;
            float iv  = sacc[16 + cc * 8 + z];
            float var = 1.0f / iv;
            float m   = sacc[cc * 8 + z];
            contrib += (-0.5f * logf(var) + 0.5f * (var + m * m) - 0.5f)
                       * (BETA / (8.0f * (float)B_));
        }
#pragma unroll
        for (int off = 32; off; off >>= 1) contrib += __shfl_down(contrib, off);
        if (tid == 0) atomicAdd(out, contrib);
    }
}

extern "C" void kernel_launch(void* const* d_in, const int* in_sizes, int n_in,
                              void* d_out, int out_size, void* d_ws, size_t ws_size,
                              hipStream_t stream)
{
    (void)in_sizes; (void)n_in; (void)out_size; (void)ws_size;
    const float* batch  = (const float*)d_in[0];
    const int*   labels = (const int*)  d_in[1];
    const float* eps1   = (const float*)d_in[2];
    const float* eps2   = (const float*)d_in[3];
    const float* W1     = (const float*)d_in[4];
    const float* b1     = (const float*)d_in[5];
    const float* W2     = (const float*)d_in[6];
    const float* b2     = (const float*)d_in[7];
    const float* Wmu    = (const float*)d_in[8];
    const float* bmu    = (const float*)d_in[9];
    const float* Wv     = (const float*)d_in[10];
    const float* bv     = (const float*)d_in[11];
    const float* sw     = (const float*)d_in[12];
    const float* sb     = (const float*)d_in[13];

    unsigned short* wf = (unsigned short*)d_ws;  // 5 frags x 64 lanes x 8 bf16

    hipMemsetAsync(d_out, 0, sizeof(float), stream);
    hib_prep<<<1, 64, 0, stream>>>(W1, W2, Wmu, Wv, wf);
    hib_mfma<<<B_, 256, 0, stream>>>(batch, labels, eps1, eps2, wf,
                                     b1, b2, bmu, bv, sw, sb, (float*)d_out);
}